// Round 12
// baseline (83.624 us; speedup 1.0000x reference)
//
#include <hip/hip_runtime.h>

// DIAGNOSTIC ROUND: R11 kernel with the gather+compute phase repeated REPS=8
// times (opaque asm prevents hoisting; acc summed over reps, scaled by exact
// 1/8). Purpose: (1) dur(8)-dur(1) = 7x marginal cost of gather+compute,
// separating it from the fixed floor; (2) at >40us the kernel enters the
// rocprof top-5 so we finally see ITS VALUBusy/FETCH/Occupancy counters.
// Output remains correct (passes absmax check).
#define NB 16
#define NN 2048
#define NM 64
#define NC 48
#define LDSP 50
#define PIF 3.14159265358979323f
#define REPS 8

struct F3 { float x, y, z; };

__global__ __launch_bounds__(256) void fused_kernel(
    const float* __restrict__ X,               // [B*N*3] f32
    const int* __restrict__ Nbrs,              // [B*N*M]
    const int* __restrict__ NbrsZ,             // [B*N*M]
    const float* __restrict__ rcg,             // [12]
    const float* __restrict__ rsg,             // [12]
    const float* __restrict__ reg,             // [12]
    float* __restrict__ out)                   // [B][N][48] f32
{
  __shared__ float sBN[2 * NB * LDSP];         // 6.4 KB: [n_local][b][50]

  const int tid = threadIdx.x;
  const int al  = tid >> 3;                    // atom_local 0..31
  const int t   = tid & 7;                     // neighbor-subset lane
  const int b   = al & 15;                     // batch
  const int nl  = al >> 4;                     // 0..1
  const int n   = blockIdx.x * 2 + nl;
  const int row = b * NN + n;

  // Index loads first (longest latency: HBM).
  const int base = row * NM + t * 8;
  const int4 j40 = *(const int4*)(Nbrs  + base);
  const int4 j41 = *(const int4*)(Nbrs  + base + 4);
  const int4 z40 = *(const int4*)(NbrsZ + base);
  const int4 z41 = *(const int4*)(NbrsZ + base + 4);

  // Uniform params (scalar-cached loads).
  const float rc4 = rcg[0], rc8 = rcg[6];
  const float re  = reg[0];
  const float nre = -re;
  const float pio8  = PIF / rc8;
  const float sp    = rsg[1] - rsg[0];
  const float gcoef = 2.f * re * sp;
  const float rs3   = rsg[3];
  const float qu4 = __expf(nre * (rsg[4] * rsg[4] - rsg[3] * rsg[3]));
  const float qu5 = __expf(nre * (rsg[5] * rsg[5] - rsg[4] * rsg[4]));
  const float qd2 = __expf(nre * (rsg[2] * rsg[2] - rsg[3] * rsg[3]));
  const float qd1 = __expf(nre * (rsg[1] * rsg[1] - rsg[2] * rsg[2]));
  const float qd0 = __expf(nre * (rsg[0] * rsg[0] - rsg[1] * rsg[1]));

  const float* xb = X + (size_t)b * (NN * 3);
  const float xi0 = xb[n * 3 + 0];
  const float yi0 = xb[n * 3 + 1];
  const float zi0 = xb[n * 3 + 2];

  const int js[8] = {j40.x, j40.y, j40.z, j40.w, j41.x, j41.y, j41.z, j41.w};
  const int zs[8] = {z40.x, z40.y, z40.z, z40.w, z41.x, z41.y, z41.z, z41.w};

  float2 acc2[24];
#pragma unroll
  for (int c = 0; c < 24; ++c) acc2[c] = make_float2(0.f, 0.f);

#pragma unroll 1
  for (int rep = 0; rep < REPS; ++rep) {
    // Opaque per-rep copies: compiler cannot hoist the gathers or the
    // R-computation out of the rep loop (addresses/centers "unknown").
    float xi = xi0, yi = yi0, zi = zi0;
    asm volatile("" : "+v"(xi), "+v"(yi), "+v"(zi));
    int js2[8];
#pragma unroll
    for (int u = 0; u < 8; ++u) {
      js2[u] = js[u];
      asm volatile("" : "+v"(js2[u]));
    }

    // Gather neighbor coords (12B dwordx3 each, L2-resident table).
    float px[8], py[8], pz[8];
#pragma unroll
    for (int u = 0; u < 8; ++u) {
      const F3 p = *(const F3*)(xb + js2[u] * 3);
      px[u] = p.x;
      py[u] = p.y;
      pz[u] = p.z;
    }

#pragma unroll
    for (int u = 0; u < 8; ++u) {
      const float dx = px[u] - xi, dy = py[u] - yi, dz = pz[u] - zi;
      const float R = sqrtf(fmaf(dx, dx, fmaf(dy, dy, dz * dz)));
      const float Rk = fminf(R, rc8);

      // Mid-anchored gaussian ladder (max intermediate e^36).
      const float u3 = Rk - rs3;
      const float K3 = __expf(nre * (u3 * u3));
      const float Gu = __expf(gcoef * Rk);
      const float Gd = __builtin_amdgcn_rcpf(Gu);
      const float K4 = K3 * Gu * qu4;
      const float K5 = K4 * Gu * qu5;
      const float K2 = K3 * Gd * qd2;
      const float K1 = K2 * Gd * qd1;
      const float K0 = K1 * Gd * qd0;
      const float K[6] = {K0, K1, K2, K3, K4, K5};

      // Cutoffs: c4 from c8 via double-angle.
      const float c8  = __cosf(pio8 * R);
      const float c4  = fmaf(c8 + c8, c8, -1.f);
      const float fc8 = (R <= rc8) ? fmaf(0.5f, c8, 0.5f) : 0.f;
      const float fc4 = (R <= rc4) ? fmaf(0.5f, c4, 0.5f) : 0.f;

      const int z = zs[u];
      const float a40 = (z == 1) ? fc4 : 0.f, a80 = (z == 1) ? fc8 : 0.f;
      const float a41 = (z == 6) ? fc4 : 0.f, a81 = (z == 6) ? fc8 : 0.f;
      const float a42 = (z == 7) ? fc4 : 0.f, a82 = (z == 7) ? fc8 : 0.f;
      const float a43 = (z == 8) ? fc4 : 0.f, a83 = (z == 8) ? fc8 : 0.f;

#pragma unroll
      for (int r = 0; r < 6; ++r) {
        const float k = K[r];
        acc2[ 0 + r].x = fmaf(a40, k, acc2[ 0 + r].x);
        acc2[ 0 + r].y = fmaf(a80, k, acc2[ 0 + r].y);
        acc2[ 6 + r].x = fmaf(a41, k, acc2[ 6 + r].x);
        acc2[ 6 + r].y = fmaf(a81, k, acc2[ 6 + r].y);
        acc2[12 + r].x = fmaf(a42, k, acc2[12 + r].x);
        acc2[12 + r].y = fmaf(a82, k, acc2[12 + r].y);
        acc2[18 + r].x = fmaf(a43, k, acc2[18 + r].x);
        acc2[18 + r].y = fmaf(a83, k, acc2[18 + r].y);
      }
    }
  }

  // Scale the 8-fold sum by exactly 1/8 (power of two: exponent shift only).
  const float scale = 1.f / (float)REPS;
  float acc[NC];
#pragma unroll
  for (int ty = 0; ty < 4; ++ty)
#pragma unroll
    for (int r = 0; r < 6; ++r) {
      acc[ty * 12 + r]     = acc2[ty * 6 + r].x * scale;
      acc[ty * 12 + 6 + r] = acc2[ty * 6 + r].y * scale;
    }

  // Funnel reduce across the 8 lanes of this atom, in place.
#pragma unroll
  for (int c = 0; c < NC; ++c) acc[c] += __shfl_xor(acc[c], 4, 64);
  const bool s4 = (t & 4) != 0;
#pragma unroll
  for (int j = 0; j < 24; ++j) acc[j] = s4 ? acc[24 + j] : acc[j];
#pragma unroll
  for (int j = 0; j < 24; ++j) acc[j] += __shfl_xor(acc[j], 2, 64);
  const bool s2 = (t & 2) != 0;
#pragma unroll
  for (int j = 0; j < 12; ++j) acc[j] = s2 ? acc[12 + j] : acc[j];
#pragma unroll
  for (int j = 0; j < 12; ++j) acc[j] += __shfl_xor(acc[j], 1, 64);
  const bool s1 = (t & 1) != 0;
  const int lb = (nl * NB + b) * LDSP + 6 * t;
#pragma unroll
  for (int j = 0; j < 6; ++j) sBN[lb + j] = s1 ? acc[6 + j] : acc[j];

  __syncthreads();

  // Batch-norm over b (16 samples) per (n, channel).
  if (tid < 128) {
    const int nn = tid >> 6;
    const int cc = tid & 63;
    if (cc < NC) {
      float x[NB];
      float s = 0.f;
#pragma unroll
      for (int bb = 0; bb < NB; ++bb) {
        x[bb] = sBN[(nn * NB + bb) * LDSP + cc];
        s += x[bb];
      }
      const float mean = s * (1.f / NB);
      float vs = 0.f;
#pragma unroll
      for (int bb = 0; bb < NB; ++bb) {
        const float d = x[bb] - mean;
        vs = fmaf(d, d, vs);
      }
      const float inv = rsqrtf(vs * (1.f / NB) + 1e-3f);
      const int ng = blockIdx.x * 2 + nn;
#pragma unroll
      for (int bb = 0; bb < NB; ++bb) {
        out[(size_t)bb * (NN * NC) + ng * NC + cc] = (x[bb] - mean) * inv;
      }
    }
  }
}

extern "C" void kernel_launch(void* const* d_in, const int* in_sizes, int n_in,
                              void* d_out, int out_size, void* d_ws, size_t ws_size,
                              hipStream_t stream) {
  const float* X   = (const float*)d_in[0];    // f32 [16,2048,3]
  const int* Nbrs  = (const int*)d_in[1];      // [16,2048,64]
  const int* NbrsZ = (const int*)d_in[2];      // [16,2048,64]
  const float* rcg = (const float*)d_in[3];    // f32 [12]
  const float* rsg = (const float*)d_in[4];    // f32 [12]
  const float* reg = (const float*)d_in[5];    // f32 [12]

  float* out = (float*)d_out;                  // f32 [16,2048,48]

  fused_kernel<<<1024, 256, 0, stream>>>(X, Nbrs, NbrsZ, rcg, rsg, reg, out);
}

// Round 13
// 18.285 us; speedup vs baseline: 4.5733x; 4.5733x over previous
//
#include <hip/hip_runtime.h>

// B=16, N=2048, M=64, L=12, A=4. Params fixed by reference setup:
// params = [[rc, rs, 4.0] for rc in (4,8) for rs in (0,1,2,3,4,5)]
// R12 diagnostic: compute is LATENCY-bound (VALUBusy 46%, Occ 23%, HBM 2%).
// Fix: 16 threads/atom x 4 neighbors (was 8x8) -> 8192 waves (2x), hiding the
// exp-ladder + L2-gather latency. Block = 256 thr = 1 n-value x 16 batches.
// Math identical to R11: mid-anchored gaussian ladder (2 exp + 1 cos + 1 rcp
// per neighbor), packed float2 accumulate (rc4,rc8) -> v_pk_fma_f32, fused BN.
#define NB 16
#define NN 2048
#define NM 64
#define NC 48
#define LDSP 49   // padded LDS row stride (floats)
#define PIF 3.14159265358979323f

struct F3 { float x, y, z; };                  // 12B dwordx3 gather

__global__ __launch_bounds__(256) void fused_kernel(
    const float* __restrict__ X,               // [B*N*3] f32
    const int* __restrict__ Nbrs,              // [B*N*M]
    const int* __restrict__ NbrsZ,             // [B*N*M]
    const float* __restrict__ rcg,             // [12]
    const float* __restrict__ rsg,             // [12]
    const float* __restrict__ reg,             // [12]
    float* __restrict__ out)                   // [B][N][48] f32
{
  __shared__ float sBN[NB * LDSP];             // 3.1 KB: [b][49]

  const int tid = threadIdx.x;
  const int b   = tid >> 4;                    // batch 0..15 (one atom per b)
  const int t   = tid & 15;                    // neighbor-subset lane 0..15
  const int n   = blockIdx.x;                  // 0..2047
  const int row = b * NN + n;

  // Index loads first (longest latency): one int4 pair per thread.
  const int base = row * NM + t * 4;
  const int4 j4 = *(const int4*)(Nbrs  + base);
  const int4 z4 = *(const int4*)(NbrsZ + base);

  // Uniform params (scalar-cached loads).
  const float rc4 = rcg[0], rc8 = rcg[6];
  const float re  = reg[0];
  const float nre = -re;
  const float pio8  = PIF / rc8;
  const float sp    = rsg[1] - rsg[0];         // uniform spacing (=1)
  const float gcoef = 2.f * re * sp;           // Gu = exp(gcoef*Rk)
  const float rs3   = rsg[3];                  // ladder anchor
  const float qu4 = __expf(nre * (rsg[4] * rsg[4] - rsg[3] * rsg[3]));
  const float qu5 = __expf(nre * (rsg[5] * rsg[5] - rsg[4] * rsg[4]));
  const float qd2 = __expf(nre * (rsg[2] * rsg[2] - rsg[3] * rsg[3]));
  const float qd1 = __expf(nre * (rsg[1] * rsg[1] - rsg[2] * rsg[2]));
  const float qd0 = __expf(nre * (rsg[0] * rsg[0] - rsg[1] * rsg[1]));

  const float* xb = X + (size_t)b * (NN * 3);
  const float xi = xb[n * 3 + 0];
  const float yi = xb[n * 3 + 1];
  const float zi = xb[n * 3 + 2];

  const int js[4] = {j4.x, j4.y, j4.z, j4.w};
  const int zs[4] = {z4.x, z4.y, z4.z, z4.w};

  // Pre-load the 4 neighbor coords (independent 12B L2 loads in flight).
  float px[4], py[4], pz[4];
#pragma unroll
  for (int u = 0; u < 4; ++u) {
    const F3 p = *(const F3*)(xb + js[u] * 3);
    px[u] = p.x;
    py[u] = p.y;
    pz[u] = p.z;
  }

  // Packed accumulator: acc2[type*6 + r] = {channel rc4, channel rc8}.
  float2 acc2[24];
#pragma unroll
  for (int c = 0; c < 24; ++c) acc2[c] = make_float2(0.f, 0.f);

#pragma unroll
  for (int u = 0; u < 4; ++u) {
    const float dx = px[u] - xi, dy = py[u] - yi, dz = pz[u] - zi;
    const float R = sqrtf(fmaf(dx, dx, fmaf(dy, dy, dz * dz)));
    const float Rk = fminf(R, rc8);            // clamp: fc==0 beyond rc8 anyway

    // Mid-anchored gaussian ladder (max intermediate e^36).
    const float u3 = Rk - rs3;
    const float K3 = __expf(nre * (u3 * u3));
    const float Gu = __expf(gcoef * Rk);       // <= e^64, finite
    const float Gd = __builtin_amdgcn_rcpf(Gu);
    const float K4 = K3 * Gu * qu4;
    const float K5 = K4 * Gu * qu5;
    const float K2 = K3 * Gd * qd2;
    const float K1 = K2 * Gd * qd1;
    const float K0 = K1 * Gd * qd0;
    const float K[6] = {K0, K1, K2, K3, K4, K5};

    // Cutoffs: c4 from c8 via double-angle (exact identity).
    const float c8  = __cosf(pio8 * R);
    const float c4  = fmaf(c8 + c8, c8, -1.f);
    const float fc8 = (R <= rc8) ? fmaf(0.5f, c8, 0.5f) : 0.f;
    const float fc4 = (R <= rc4) ? fmaf(0.5f, c4, 0.5f) : 0.f;

    // Type mask folded into cndmask selects.
    const int z = zs[u];
    const float a40 = (z == 1) ? fc4 : 0.f, a80 = (z == 1) ? fc8 : 0.f;
    const float a41 = (z == 6) ? fc4 : 0.f, a81 = (z == 6) ? fc8 : 0.f;
    const float a42 = (z == 7) ? fc4 : 0.f, a82 = (z == 7) ? fc8 : 0.f;
    const float a43 = (z == 8) ? fc4 : 0.f, a83 = (z == 8) ? fc8 : 0.f;

    // 24 packed FMAs (v_pk_fma_f32).
#pragma unroll
    for (int r = 0; r < 6; ++r) {
      const float k = K[r];
      acc2[ 0 + r].x = fmaf(a40, k, acc2[ 0 + r].x);
      acc2[ 0 + r].y = fmaf(a80, k, acc2[ 0 + r].y);
      acc2[ 6 + r].x = fmaf(a41, k, acc2[ 6 + r].x);
      acc2[ 6 + r].y = fmaf(a81, k, acc2[ 6 + r].y);
      acc2[12 + r].x = fmaf(a42, k, acc2[12 + r].x);
      acc2[12 + r].y = fmaf(a82, k, acc2[12 + r].y);
      acc2[18 + r].x = fmaf(a43, k, acc2[18 + r].x);
      acc2[18 + r].y = fmaf(a83, k, acc2[18 + r].y);
    }
  }

  // Unpack to channel order: c = type*12 + rcgrp*6 + r.
  float acc[NC];
#pragma unroll
  for (int ty = 0; ty < 4; ++ty)
#pragma unroll
    for (int r = 0; r < 6; ++r) {
      acc[ty * 12 + r]     = acc2[ty * 6 + r].x;
      acc[ty * 12 + 6 + r] = acc2[ty * 6 + r].y;
    }

  // Funnel reduce across the 16 lanes of this atom (lanes 16b..16b+15),
  // folded in place. Lane t ends owning channels [3t, 3t+3).
#pragma unroll
  for (int c = 0; c < NC; ++c) acc[c] += __shfl_xor(acc[c], 8, 64);
  const bool s8 = (t & 8) != 0;
#pragma unroll
  for (int j = 0; j < 24; ++j) acc[j] = s8 ? acc[24 + j] : acc[j];
#pragma unroll
  for (int j = 0; j < 24; ++j) acc[j] += __shfl_xor(acc[j], 4, 64);
  const bool s4 = (t & 4) != 0;
#pragma unroll
  for (int j = 0; j < 12; ++j) acc[j] = s4 ? acc[12 + j] : acc[j];
#pragma unroll
  for (int j = 0; j < 12; ++j) acc[j] += __shfl_xor(acc[j], 2, 64);
  const bool s2 = (t & 2) != 0;
#pragma unroll
  for (int j = 0; j < 6; ++j) acc[j] = s2 ? acc[6 + j] : acc[j];
#pragma unroll
  for (int j = 0; j < 6; ++j) acc[j] += __shfl_xor(acc[j], 1, 64);
  const bool s1 = (t & 1) != 0;
#pragma unroll
  for (int j = 0; j < 3; ++j) acc[j] = s1 ? acc[3 + j] : acc[j];

  const int lb = b * LDSP + 3 * t;
  sBN[lb + 0] = acc[0];
  sBN[lb + 1] = acc[1];
  sBN[lb + 2] = acc[2];

  __syncthreads();

  // Batch-norm over b (16 samples); threads 0..47 each own one channel.
  if (tid < NC) {
    const int cc = tid;
    float x[NB];
    float s = 0.f;
#pragma unroll
    for (int bb = 0; bb < NB; ++bb) {
      x[bb] = sBN[bb * LDSP + cc];
      s += x[bb];
    }
    const float mean = s * (1.f / NB);
    float vs = 0.f;
#pragma unroll
    for (int bb = 0; bb < NB; ++bb) {
      const float d = x[bb] - mean;
      vs = fmaf(d, d, vs);
    }
    const float inv = rsqrtf(vs * (1.f / NB) + 1e-3f);
#pragma unroll
    for (int bb = 0; bb < NB; ++bb) {
      out[(size_t)bb * (NN * NC) + n * NC + cc] = (x[bb] - mean) * inv;
    }
  }
}

extern "C" void kernel_launch(void* const* d_in, const int* in_sizes, int n_in,
                              void* d_out, int out_size, void* d_ws, size_t ws_size,
                              hipStream_t stream) {
  const float* X   = (const float*)d_in[0];    // f32 [16,2048,3]
  const int* Nbrs  = (const int*)d_in[1];      // [16,2048,64]
  const int* NbrsZ = (const int*)d_in[2];      // [16,2048,64]
  const float* rcg = (const float*)d_in[3];    // f32 [12]
  const float* rsg = (const float*)d_in[4];    // f32 [12]
  const float* reg = (const float*)d_in[5];    // f32 [12]

  float* out = (float*)d_out;                  // f32 [16,2048,48]

  // 2048 blocks: one n-value x 16 batches each; 8192 waves total.
  fused_kernel<<<2048, 256, 0, stream>>>(X, Nbrs, NbrsZ, rcg, rsg, reg, out);
}